// Round 3
// baseline (379.685 us; speedup 1.0000x reference)
//
#include <hip/hip_runtime.h>
#include <cstdint>
#include <cstddef>

typedef __bf16 bhalf;
typedef __bf16 bhalf8 __attribute__((ext_vector_type(8)));
typedef __bf16 bhalf4 __attribute__((ext_vector_type(4)));
typedef float f32x4 __attribute__((ext_vector_type(4)));

#define RMS_EPS 1e-6f
#define N_HEADS 16
#define N_KV 4
#define HD 128
#define DIM 2048
#define SEQ 2048
#define BATCH 2

static __device__ __forceinline__ f32x4 mfma16(bhalf8 a, bhalf8 b, f32x4 c) {
    return __builtin_amdgcn_mfma_f32_16x16x32_bf16(a, b, c, 0, 0, 0);
}

// async global->LDS, 16B per lane; l must be wave-uniform base (HW adds lane*16)
static __device__ __forceinline__ void gload16(const bhalf* g, bhalf* l) {
    __builtin_amdgcn_global_load_lds((const __attribute__((address_space(1))) unsigned int*)g,
                                     (__attribute__((address_space(3))) unsigned int*)l,
                                     16, 0, 0);
}

// ---------------- weight convert f32 -> bf16 ----------------
__global__ __launch_bounds__(256) void cvt_w(const float* __restrict__ a,
                                             const float* __restrict__ b,
                                             bhalf* __restrict__ dst) {
    size_t i = ((size_t)blockIdx.x * 256 + threadIdx.x) * 4;
    const size_t NQ = (size_t)3072 * 2048;
    float4 v = (i < NQ) ? ((const float4*)a)[i >> 2] : ((const float4*)b)[(i - NQ) >> 2];
    bhalf4 o;
    o[0] = (bhalf)v.x; o[1] = (bhalf)v.y; o[2] = (bhalf)v.z; o[3] = (bhalf)v.w;
    *(bhalf4*)(dst + i) = o;
}

// ---------------- RMSNorm: one block per row ----------------
__global__ __launch_bounds__(256) void rmsnorm_k(const float* __restrict__ x,
                                                 const float* __restrict__ w,
                                                 bhalf* __restrict__ xn) {
    const int row = blockIdx.x;
    const int tid = threadIdx.x;
    const float4* xr = (const float4*)(x + (size_t)row * DIM);
    float4 v0 = xr[tid * 2], v1 = xr[tid * 2 + 1];
    float ss = v0.x * v0.x + v0.y * v0.y + v0.z * v0.z + v0.w * v0.w
             + v1.x * v1.x + v1.y * v1.y + v1.z * v1.z + v1.w * v1.w;
    #pragma unroll
    for (int off = 32; off; off >>= 1) ss += __shfl_xor(ss, off, 64);
    __shared__ float red[4];
    if ((tid & 63) == 0) red[tid >> 6] = ss;
    __syncthreads();
    float tot = red[0] + red[1] + red[2] + red[3];
    float scale = rsqrtf(tot * (1.0f / DIM) + RMS_EPS);
    const float4* wr = (const float4*)w;
    float4 w0 = wr[tid * 2], w1 = wr[tid * 2 + 1];
    bhalf8 o;
    o[0] = (bhalf)(v0.x * scale * w0.x); o[1] = (bhalf)(v0.y * scale * w0.y);
    o[2] = (bhalf)(v0.z * scale * w0.z); o[3] = (bhalf)(v0.w * scale * w0.w);
    o[4] = (bhalf)(v1.x * scale * w1.x); o[5] = (bhalf)(v1.y * scale * w1.y);
    o[6] = (bhalf)(v1.z * scale * w1.z); o[7] = (bhalf)(v1.w * scale * w1.w);
    *(bhalf8*)(xn + (size_t)row * DIM + tid * 8) = o;
}

// ---------------- GEMM C = A * B^T (m97 structure: global_load_lds) --------
// A: M x K, B: N x K, C: M x N.  Tile 128x128, BK=32, 4 waves (2x2 of 64x64).
__global__ __launch_bounds__(256) void gemm_abt(const bhalf* __restrict__ A,
                                                const bhalf* __restrict__ B,
                                                float* __restrict__ C,
                                                int N, int K) {
    const int tid = threadIdx.x;
    const int wave = tid >> 6, lane = tid & 63;
    const int quad = lane >> 4, r16 = lane & 15;
    const int m0 = blockIdx.y * 128, n0 = blockIdx.x * 128;
    const int wm = (wave >> 1) * 64, wn = (wave & 1) * 64;

    __shared__ __align__(16) bhalf sA[128][32];
    __shared__ __align__(16) bhalf sB[128][32];

    f32x4 acc[4][4];
    #pragma unroll
    for (int i = 0; i < 4; ++i)
        #pragma unroll
        for (int j = 0; j < 4; ++j) acc[i][j] = (f32x4)0.0f;

    // staging: wave w covers rows 32w..32w+31 (two 16-row chunks), lane->row/col
    const int lrow = lane >> 2;          // 0..15
    const int lcol = (lane & 3) * 8;     // elements
    const int arow = 32 * wave + lrow;
    const bhalf* Ap = A + (size_t)(m0 + arow) * K + lcol;
    const bhalf* Bp = B + (size_t)(n0 + arow) * K + lcol;
    const size_t rs16 = (size_t)16 * K;
    bhalf* sAp0 = &sA[32 * wave][0];
    bhalf* sAp1 = &sA[32 * wave + 16][0];
    bhalf* sBp0 = &sB[32 * wave][0];
    bhalf* sBp1 = &sB[32 * wave + 16][0];

    for (int k0 = 0; k0 < K; k0 += 32) {
        __syncthreads();
        gload16(Ap + k0, sAp0);
        gload16(Ap + k0 + rs16, sAp1);
        gload16(Bp + k0, sBp0);
        gload16(Bp + k0 + rs16, sBp1);
        __syncthreads();
        bhalf8 af[4], bfr[4];
        #pragma unroll
        for (int i = 0; i < 4; ++i) af[i]  = *(bhalf8*)&sA[wm + i * 16 + r16][quad * 8];
        #pragma unroll
        for (int j = 0; j < 4; ++j) bfr[j] = *(bhalf8*)&sB[wn + j * 16 + r16][quad * 8];
        #pragma unroll
        for (int i = 0; i < 4; ++i)
            #pragma unroll
            for (int j = 0; j < 4; ++j)
                acc[i][j] = mfma16(af[i], bfr[j], acc[i][j]);
    }

    #pragma unroll
    for (int i = 0; i < 4; ++i) {
        const int rbase = m0 + wm + i * 16 + quad * 4;
        #pragma unroll
        for (int rr = 0; rr < 4; ++rr) {
            float* crow = C + (size_t)(rbase + rr) * N + n0 + wn + r16;
            #pragma unroll
            for (int j = 0; j < 4; ++j) crow[j * 16] = acc[i][j][rr];
        }
    }
}

// ---------------- RoPE + repack q/k, transpose v ----------------
__global__ __launch_bounds__(256) void rope_k(const float* __restrict__ qkv,
                                              const float* __restrict__ freqs,
                                              bhalf* __restrict__ qb,
                                              bhalf* __restrict__ kb,
                                              bhalf* __restrict__ vt) {
    const int bs = blockIdx.x;
    const int b = bs >> 11, s = bs & 2047;
    const float* row = qkv + (size_t)bs * 3072;
    const int tid = threadIdx.x;

    {
        const int h = tid >> 4, d20 = (tid & 15) * 4;
        const float* rp = row + h * HD + d20 * 2;
        float4 e0 = *(const float4*)rp;
        float4 e1 = *(const float4*)(rp + 4);
        const float* fp = freqs + (size_t)s * 128 + d20 * 2;
        float4 f0 = *(const float4*)fp;
        float4 f1 = *(const float4*)(fp + 4);
        bhalf8 o;
        o[0] = (bhalf)(e0.x * f0.x - e0.y * f0.y); o[1] = (bhalf)(e0.x * f0.y + e0.y * f0.x);
        o[2] = (bhalf)(e0.z * f0.z - e0.w * f0.w); o[3] = (bhalf)(e0.z * f0.w + e0.w * f0.z);
        o[4] = (bhalf)(e1.x * f1.x - e1.y * f1.y); o[5] = (bhalf)(e1.x * f1.y + e1.y * f1.x);
        o[6] = (bhalf)(e1.z * f1.z - e1.w * f1.w); o[7] = (bhalf)(e1.z * f1.w + e1.w * f1.z);
        *(bhalf8*)(qb + ((size_t)(b * N_HEADS + h) * SEQ + s) * HD + d20 * 2) = o;
    }
    if (tid < 64) {
        const int kh = tid >> 4, d20 = (tid & 15) * 4;
        const float* rp = row + 2048 + kh * HD + d20 * 2;
        float4 e0 = *(const float4*)rp;
        float4 e1 = *(const float4*)(rp + 4);
        const float* fp = freqs + (size_t)s * 128 + d20 * 2;
        float4 f0 = *(const float4*)fp;
        float4 f1 = *(const float4*)(fp + 4);
        bhalf8 o;
        o[0] = (bhalf)(e0.x * f0.x - e0.y * f0.y); o[1] = (bhalf)(e0.x * f0.y + e0.y * f0.x);
        o[2] = (bhalf)(e0.z * f0.z - e0.w * f0.w); o[3] = (bhalf)(e0.z * f0.w + e0.w * f0.z);
        o[4] = (bhalf)(e1.x * f1.x - e1.y * f1.y); o[5] = (bhalf)(e1.x * f1.y + e1.y * f1.x);
        o[6] = (bhalf)(e1.z * f1.z - e1.w * f1.w); o[7] = (bhalf)(e1.z * f1.w + e1.w * f1.z);
        *(bhalf8*)(kb + ((size_t)(b * N_KV + kh) * SEQ + s) * HD + d20 * 2) = o;
    }
    for (int e = tid; e < 512; e += 256) {
        const int kh = e >> 7, d = e & 127;
        vt[((size_t)(b * N_KV + kh) * HD + d) * SEQ + s] = (bhalf)row[2560 + e];
    }
}

// ---------------- Flash attention (24 balanced groups, 3 blocks/CU) --------
// grid: (24 groups, 32 bh). groups 0..15: singleton qt=16+g (17..32 iters);
// groups 16..23: pair (g-16, 15-(g-16)) (17 iters). 256 thr = 4 waves x 16 rows.
__global__ __launch_bounds__(256, 3) void attn_k(const bhalf* __restrict__ qb,
                                                 const bhalf* __restrict__ kb,
                                                 const bhalf* __restrict__ vt,
                                                 bhalf* __restrict__ ob) {
    const int tid = threadIdx.x;
    const int wave = tid >> 6, lane = tid & 63;
    const int quad = lane >> 4, r16 = lane & 15;
    const int grp = blockIdx.x;
    const int h = blockIdx.y & 15;
    const int b = blockIdx.y >> 4;
    const int kvh = h >> 2;

    int nq, qts[2];
    if (grp < 16) { nq = 1; qts[0] = 16 + grp; qts[1] = 0; }
    else          { nq = 2; qts[0] = grp - 16; qts[1] = 15 - (grp - 16); }

    __shared__ __align__(16) bhalf sK[64][136];
    __shared__ __align__(16) bhalf sV[128][72];
    __shared__ __align__(16) bhalf sP[4][16][72];

    const bhalf* Kbase = kb + (size_t)(b * N_KV + kvh) * SEQ * HD;
    const bhalf* Vbase = vt + (size_t)(b * N_KV + kvh) * HD * SEQ;
    const float SCL2 = 0.08838834764831845f * 1.4426950408889634f;

    const int kr = tid >> 4, kc = (tid & 15) * 8;   // K rows kr+16i, col kc
    const int vr = tid >> 3, vc = (tid & 7) * 8;    // V^T rows vr+32i, col vc

    for (int phase = 0; phase < nq; ++phase) {
        const int qt = qts[phase];

        const bhalf* qbase = qb + (((size_t)(b * N_HEADS + h) * SEQ) + qt * 64 + wave * 16 + r16) * HD;
        bhalf8 qf[4];
        #pragma unroll
        for (int kk = 0; kk < 4; ++kk) {
            bhalf8 q0 = *(const bhalf8*)(qbase + kk * 32 + quad * 8);
            #pragma unroll
            for (int e = 0; e < 8; ++e) q0[e] = (bhalf)((float)q0[e] * SCL2);
            qf[kk] = q0;
        }

        f32x4 accO[8];
        #pragma unroll
        for (int dt = 0; dt < 8; ++dt) accO[dt] = (f32x4)0.0f;
        float m_i[4], l_i[4];
        #pragma unroll
        for (int r = 0; r < 4; ++r) { m_i[r] = -1e30f; l_i[r] = 0.0f; }

        bhalf8 kreg[4], vreg[4];
        #pragma unroll
        for (int i = 0; i < 4; ++i) {
            kreg[i] = *(const bhalf8*)(Kbase + (size_t)(kr + 16 * i) * HD + kc);
            vreg[i] = *(const bhalf8*)(Vbase + (size_t)(vr + 32 * i) * SEQ + vc);
        }

        for (int kt = 0; kt <= qt; ++kt) {
            __syncthreads();
            #pragma unroll
            for (int i = 0; i < 4; ++i) {
                *(bhalf8*)&sK[kr + 16 * i][kc] = kreg[i];
                *(bhalf8*)&sV[vr + 32 * i][vc] = vreg[i];
            }
            __syncthreads();
            if (kt < qt) {
                const int kn = (kt + 1) * 64;
                #pragma unroll
                for (int i = 0; i < 4; ++i) {
                    kreg[i] = *(const bhalf8*)(Kbase + (size_t)(kn + kr + 16 * i) * HD + kc);
                    vreg[i] = *(const bhalf8*)(Vbase + (size_t)(vr + 32 * i) * SEQ + kn + vc);
                }
            }

            f32x4 accS[4];
            #pragma unroll
            for (int nt = 0; nt < 4; ++nt) accS[nt] = (f32x4)0.0f;
            #pragma unroll
            for (int nt = 0; nt < 4; ++nt)
                #pragma unroll
                for (int kk = 0; kk < 4; ++kk) {
                    bhalf8 kf = *(bhalf8*)&sK[nt * 16 + r16][kk * 32 + quad * 8];
                    accS[nt] = mfma16(qf[kk], kf, accS[nt]);
                }
            if (kt == qt) {
                #pragma unroll
                for (int nt = 0; nt < 4; ++nt)
                    #pragma unroll
                    for (int r = 0; r < 4; ++r)
                        if (nt * 16 + r16 > wave * 16 + quad * 4 + r) accS[nt][r] = -1e30f;
            }

            float mnew[4], alpha[4];
            #pragma unroll
            for (int r = 0; r < 4; ++r) {
                float mx = fmaxf(fmaxf(accS[0][r], accS[1][r]), fmaxf(accS[2][r], accS[3][r]));
                #pragma unroll
                for (int off = 8; off; off >>= 1) mx = fmaxf(mx, __shfl_xor(mx, off, 16));
                mnew[r] = fmaxf(m_i[r], mx);
                alpha[r] = exp2f(m_i[r] - mnew[r]);
                m_i[r] = mnew[r];
            }
            float rs[4] = {0.f, 0.f, 0.f, 0.f};
            #pragma unroll
            for (int nt = 0; nt < 4; ++nt)
                #pragma unroll
                for (int r = 0; r < 4; ++r) {
                    float p = exp2f(accS[nt][r] - mnew[r]);
                    sP[wave][quad * 4 + r][nt * 16 + r16] = (bhalf)p;
                    rs[r] += p;
                }
            #pragma unroll
            for (int r = 0; r < 4; ++r) {
                float s = rs[r];
                #pragma unroll
                for (int off = 8; off; off >>= 1) s += __shfl_xor(s, off, 16);
                l_i[r] = l_i[r] * alpha[r] + s;
            }
            #pragma unroll
            for (int dt = 0; dt < 8; ++dt)
                #pragma unroll
                for (int r = 0; r < 4; ++r) accO[dt][r] *= alpha[r];

            #pragma unroll
            for (int kk2 = 0; kk2 < 2; ++kk2) {
                bhalf8 pf = *(bhalf8*)&sP[wave][r16][kk2 * 32 + quad * 8];
                #pragma unroll
                for (int dt = 0; dt < 8; ++dt) {
                    bhalf8 vf = *(bhalf8*)&sV[dt * 16 + r16][kk2 * 32 + quad * 8];
                    accO[dt] = mfma16(pf, vf, accO[dt]);
                }
            }
        }

        float inv[4];
        #pragma unroll
        for (int r = 0; r < 4; ++r) inv[r] = 1.0f / l_i[r];
        const size_t obase = ((size_t)b * SEQ + qt * 64 + wave * 16) * (size_t)(N_HEADS * HD) + h * HD;
        #pragma unroll
        for (int dt = 0; dt < 8; ++dt)
            #pragma unroll
            for (int r = 0; r < 4; ++r)
                ob[obase + (size_t)(quad * 4 + r) * (N_HEADS * HD) + dt * 16 + r16] =
                    (bhalf)(accO[dt][r] * inv[r]);
    }
}

extern "C" void kernel_launch(void* const* d_in, const int* in_sizes, int n_in,
                              void* d_out, int out_size, void* d_ws, size_t ws_size,
                              hipStream_t stream) {
    const float* x      = (const float*)d_in[0];
    const float* freqs  = (const float*)d_in[1];
    const float* norm_w = (const float*)d_in[2];
    const float* wqkv   = (const float*)d_in[3];
    const float* wo     = (const float*)d_in[4];
    float* out = (float*)d_out;

    char* ws = (char*)d_ws;
    bhalf* wqkv_b = (bhalf*)(ws);                      // 12,582,912
    bhalf* wo_b   = (bhalf*)(ws + 12582912);           //  8,388,608
    bhalf* xn     = (bhalf*)(ws + 20971520);           // 16,777,216
    float* qkv    = (float*)(ws + 37748736);           // 50,331,648
    bhalf* qb     = (bhalf*)(ws + 88080384);           // 16,777,216
    bhalf* kb     = (bhalf*)(ws + 104857600);          //  4,194,304
    bhalf* vtb    = (bhalf*)(ws + 109051904);          //  4,194,304
    bhalf* attn   = (bhalf*)(ws + 113246208);          // 16,777,216

    cvt_w<<<10240, 256, 0, stream>>>(wqkv, wo, wqkv_b);
    rmsnorm_k<<<BATCH * SEQ, 256, 0, stream>>>(x, norm_w, xn);
    gemm_abt<<<dim3(24, 32), 256, 0, stream>>>(xn, wqkv_b, qkv, 3072, 2048);
    rope_k<<<BATCH * SEQ, 256, 0, stream>>>(qkv, freqs, qb, kb, vtb);
    attn_k<<<dim3(24, 32), 256, 0, stream>>>(qb, kb, vtb, attn);
    gemm_abt<<<dim3(16, 32), 256, 0, stream>>>(attn, wo_b, out, 2048, 2048);
}

// Round 4
// 341.345 us; speedup vs baseline: 1.1123x; 1.1123x over previous
//
#include <hip/hip_runtime.h>
#include <cstdint>
#include <cstddef>

typedef __bf16 bhalf;
typedef __bf16 bhalf8 __attribute__((ext_vector_type(8)));
typedef __bf16 bhalf4 __attribute__((ext_vector_type(4)));
typedef float f32x4 __attribute__((ext_vector_type(4)));

#define RMS_EPS 1e-6f
#define N_HEADS 16
#define N_KV 4
#define HD 128
#define DIM 2048
#define SEQ 2048
#define BATCH 2

static __device__ __forceinline__ f32x4 mfma16(bhalf8 a, bhalf8 b, f32x4 c) {
    return __builtin_amdgcn_mfma_f32_16x16x32_bf16(a, b, c, 0, 0, 0);
}

// async global->LDS, 16B per lane; LDS base wave-uniform (HW adds lane*16)
static __device__ __forceinline__ void gload16(const bhalf* g, bhalf* l) {
    __builtin_amdgcn_global_load_lds((const __attribute__((address_space(1))) unsigned int*)g,
                                     (__attribute__((address_space(3))) unsigned int*)l,
                                     16, 0, 0);
}

// ---------------- weight convert f32 -> bf16 ----------------
__global__ __launch_bounds__(256) void cvt_w(const float* __restrict__ a,
                                             const float* __restrict__ b,
                                             bhalf* __restrict__ dst) {
    size_t i = ((size_t)blockIdx.x * 256 + threadIdx.x) * 4;
    const size_t NQ = (size_t)3072 * 2048;
    float4 v = (i < NQ) ? ((const float4*)a)[i >> 2] : ((const float4*)b)[(i - NQ) >> 2];
    bhalf4 o;
    o[0] = (bhalf)v.x; o[1] = (bhalf)v.y; o[2] = (bhalf)v.z; o[3] = (bhalf)v.w;
    *(bhalf4*)(dst + i) = o;
}

// ---------------- RMSNorm: one block per row ----------------
__global__ __launch_bounds__(256) void rmsnorm_k(const float* __restrict__ x,
                                                 const float* __restrict__ w,
                                                 bhalf* __restrict__ xn) {
    const int row = blockIdx.x;
    const int tid = threadIdx.x;
    const float4* xr = (const float4*)(x + (size_t)row * DIM);
    float4 v0 = xr[tid * 2], v1 = xr[tid * 2 + 1];
    float ss = v0.x * v0.x + v0.y * v0.y + v0.z * v0.z + v0.w * v0.w
             + v1.x * v1.x + v1.y * v1.y + v1.z * v1.z + v1.w * v1.w;
    #pragma unroll
    for (int off = 32; off; off >>= 1) ss += __shfl_xor(ss, off, 64);
    __shared__ float red[4];
    if ((tid & 63) == 0) red[tid >> 6] = ss;
    __syncthreads();
    float tot = red[0] + red[1] + red[2] + red[3];
    float scale = rsqrtf(tot * (1.0f / DIM) + RMS_EPS);
    const float4* wr = (const float4*)w;
    float4 w0 = wr[tid * 2], w1 = wr[tid * 2 + 1];
    bhalf8 o;
    o[0] = (bhalf)(v0.x * scale * w0.x); o[1] = (bhalf)(v0.y * scale * w0.y);
    o[2] = (bhalf)(v0.z * scale * w0.z); o[3] = (bhalf)(v0.w * scale * w0.w);
    o[4] = (bhalf)(v1.x * scale * w1.x); o[5] = (bhalf)(v1.y * scale * w1.y);
    o[6] = (bhalf)(v1.z * scale * w1.z); o[7] = (bhalf)(v1.w * scale * w1.w);
    *(bhalf8*)(xn + (size_t)row * DIM + tid * 8) = o;
}

// ---------------- GEMM C = A * B^T (m97 structure: global_load_lds) --------
__global__ __launch_bounds__(256) void gemm_abt(const bhalf* __restrict__ A,
                                                const bhalf* __restrict__ B,
                                                float* __restrict__ C,
                                                int N, int K) {
    const int tid = threadIdx.x;
    const int wave = tid >> 6, lane = tid & 63;
    const int quad = lane >> 4, r16 = lane & 15;
    const int m0 = blockIdx.y * 128, n0 = blockIdx.x * 128;
    const int wm = (wave >> 1) * 64, wn = (wave & 1) * 64;

    __shared__ __align__(16) bhalf sA[128][32];
    __shared__ __align__(16) bhalf sB[128][32];

    f32x4 acc[4][4];
    #pragma unroll
    for (int i = 0; i < 4; ++i)
        #pragma unroll
        for (int j = 0; j < 4; ++j) acc[i][j] = (f32x4)0.0f;

    const int lrow = lane >> 2;
    const int lcol = (lane & 3) * 8;
    const int arow = 32 * wave + lrow;
    const bhalf* Ap = A + (size_t)(m0 + arow) * K + lcol;
    const bhalf* Bp = B + (size_t)(n0 + arow) * K + lcol;
    const size_t rs16 = (size_t)16 * K;
    bhalf* sAp0 = &sA[32 * wave][0];
    bhalf* sAp1 = &sA[32 * wave + 16][0];
    bhalf* sBp0 = &sB[32 * wave][0];
    bhalf* sBp1 = &sB[32 * wave + 16][0];

    for (int k0 = 0; k0 < K; k0 += 32) {
        __syncthreads();
        gload16(Ap + k0, sAp0);
        gload16(Ap + k0 + rs16, sAp1);
        gload16(Bp + k0, sBp0);
        gload16(Bp + k0 + rs16, sBp1);
        __syncthreads();
        bhalf8 af[4], bfr[4];
        #pragma unroll
        for (int i = 0; i < 4; ++i) af[i]  = *(bhalf8*)&sA[wm + i * 16 + r16][quad * 8];
        #pragma unroll
        for (int j = 0; j < 4; ++j) bfr[j] = *(bhalf8*)&sB[wn + j * 16 + r16][quad * 8];
        #pragma unroll
        for (int i = 0; i < 4; ++i)
            #pragma unroll
            for (int j = 0; j < 4; ++j)
                acc[i][j] = mfma16(af[i], bfr[j], acc[i][j]);
    }

    #pragma unroll
    for (int i = 0; i < 4; ++i) {
        const int rbase = m0 + wm + i * 16 + quad * 4;
        #pragma unroll
        for (int rr = 0; rr < 4; ++rr) {
            float* crow = C + (size_t)(rbase + rr) * N + n0 + wn + r16;
            #pragma unroll
            for (int j = 0; j < 4; ++j) crow[j * 16] = acc[i][j][rr];
        }
    }
}

// ---------------- RoPE + repack q/k, transpose v ----------------
__global__ __launch_bounds__(256) void rope_k(const float* __restrict__ qkv,
                                              const float* __restrict__ freqs,
                                              bhalf* __restrict__ qb,
                                              bhalf* __restrict__ kb,
                                              bhalf* __restrict__ vt) {
    const int bs = blockIdx.x;
    const int b = bs >> 11, s = bs & 2047;
    const float* row = qkv + (size_t)bs * 3072;
    const int tid = threadIdx.x;

    {
        const int h = tid >> 4, d20 = (tid & 15) * 4;
        const float* rp = row + h * HD + d20 * 2;
        float4 e0 = *(const float4*)rp;
        float4 e1 = *(const float4*)(rp + 4);
        const float* fp = freqs + (size_t)s * 128 + d20 * 2;
        float4 f0 = *(const float4*)fp;
        float4 f1 = *(const float4*)(fp + 4);
        bhalf8 o;
        o[0] = (bhalf)(e0.x * f0.x - e0.y * f0.y); o[1] = (bhalf)(e0.x * f0.y + e0.y * f0.x);
        o[2] = (bhalf)(e0.z * f0.z - e0.w * f0.w); o[3] = (bhalf)(e0.z * f0.w + e0.w * f0.z);
        o[4] = (bhalf)(e1.x * f1.x - e1.y * f1.y); o[5] = (bhalf)(e1.x * f1.y + e1.y * f1.x);
        o[6] = (bhalf)(e1.z * f1.z - e1.w * f1.w); o[7] = (bhalf)(e1.z * f1.w + e1.w * f1.z);
        *(bhalf8*)(qb + ((size_t)(b * N_HEADS + h) * SEQ + s) * HD + d20 * 2) = o;
    }
    if (tid < 64) {
        const int kh = tid >> 4, d20 = (tid & 15) * 4;
        const float* rp = row + 2048 + kh * HD + d20 * 2;
        float4 e0 = *(const float4*)rp;
        float4 e1 = *(const float4*)(rp + 4);
        const float* fp = freqs + (size_t)s * 128 + d20 * 2;
        float4 f0 = *(const float4*)fp;
        float4 f1 = *(const float4*)(fp + 4);
        bhalf8 o;
        o[0] = (bhalf)(e0.x * f0.x - e0.y * f0.y); o[1] = (bhalf)(e0.x * f0.y + e0.y * f0.x);
        o[2] = (bhalf)(e0.z * f0.z - e0.w * f0.w); o[3] = (bhalf)(e0.z * f0.w + e0.w * f0.z);
        o[4] = (bhalf)(e1.x * f1.x - e1.y * f1.y); o[5] = (bhalf)(e1.x * f1.y + e1.y * f1.x);
        o[6] = (bhalf)(e1.z * f1.z - e1.w * f1.w); o[7] = (bhalf)(e1.z * f1.w + e1.w * f1.z);
        *(bhalf8*)(kb + ((size_t)(b * N_KV + kh) * SEQ + s) * HD + d20 * 2) = o;
    }
    for (int e = tid; e < 512; e += 256) {
        const int kh = e >> 7, d = e & 127;
        vt[((size_t)(b * N_KV + kh) * HD + d) * SEQ + s] = (bhalf)row[2560 + e];
    }
}

// ---------------- Flash attention: S^T formulation, 16 balanced pairs ------
// grid 512 = pair(16) | h(16) | b(2); each block: q-tiles (p, 31-p), 33 iters.
// 4 waves x 16 q-rows. S computed transposed (A=K, B=Q): each lane holds 16
// scores for ONE query (lane&15) -> 2-shuffle reductions, packed b64 P writes.
__global__ __launch_bounds__(256, 2) void attn_k(const bhalf* __restrict__ qb,
                                                 const bhalf* __restrict__ kb,
                                                 const bhalf* __restrict__ vt,
                                                 bhalf* __restrict__ ob) {
    const int tid = threadIdx.x;
    const int wave = tid >> 6, lane = tid & 63;
    const int quad = lane >> 4, r16 = lane & 15;
    const int pair = blockIdx.x & 15;
    const int h = (blockIdx.x >> 4) & 15;
    const int b = blockIdx.x >> 8;
    const int kvh = h >> 2;

    __shared__ __align__(16) bhalf sK[64][136];
    __shared__ __align__(16) bhalf sV[128][72];
    __shared__ __align__(16) bhalf sP[4][16][72];

    const bhalf* Kbase = kb + (size_t)(b * N_KV + kvh) * SEQ * HD;
    const bhalf* Vbase = vt + (size_t)(b * N_KV + kvh) * HD * SEQ;
    const float SCL2 = 0.08838834764831845f * 1.4426950408889634f;

    const int kr = tid >> 4, kc = (tid & 15) * 8;   // K rows kr+16i, col kc
    const int vr = tid >> 3, vc = (tid & 7) * 8;    // V^T rows vr+32i, col vc
    const int gat = (lane & 48);                     // quad-preserving gather base

    for (int phase = 0; phase < 2; ++phase) {
        const int qt = phase ? (31 - pair) : pair;

        // Q fragments (B-operand layout == old A-operand data), scale folded
        const bhalf* qbase = qb + (((size_t)(b * N_HEADS + h) * SEQ) + qt * 64 + wave * 16 + r16) * HD;
        bhalf8 qf[4];
        #pragma unroll
        for (int kk = 0; kk < 4; ++kk) {
            bhalf8 q0 = *(const bhalf8*)(qbase + kk * 32 + quad * 8);
            #pragma unroll
            for (int e = 0; e < 8; ++e) q0[e] = (bhalf)((float)q0[e] * SCL2);
            qf[kk] = q0;
        }

        f32x4 accO[8];
        #pragma unroll
        for (int dt = 0; dt < 8; ++dt) accO[dt] = (f32x4)0.0f;
        float m_i = -1e30f, l_i = 0.0f;   // stats for query (wave*16 + r16)

        bhalf8 kreg[4], vreg[4];
        #pragma unroll
        for (int i = 0; i < 4; ++i) {
            kreg[i] = *(const bhalf8*)(Kbase + (size_t)(kr + 16 * i) * HD + kc);
            vreg[i] = *(const bhalf8*)(Vbase + (size_t)(vr + 32 * i) * SEQ + vc);
        }

        for (int kt = 0; kt <= qt; ++kt) {
            __syncthreads();
            #pragma unroll
            for (int i = 0; i < 4; ++i) {
                *(bhalf8*)&sK[kr + 16 * i][kc] = kreg[i];
                *(bhalf8*)&sV[vr + 32 * i][vc] = vreg[i];
            }
            __syncthreads();
            if (kt < qt) {
                const int kn = (kt + 1) * 64;
                #pragma unroll
                for (int i = 0; i < 4; ++i) {
                    kreg[i] = *(const bhalf8*)(Kbase + (size_t)(kn + kr + 16 * i) * HD + kc);
                    vreg[i] = *(const bhalf8*)(Vbase + (size_t)(vr + 32 * i) * SEQ + kn + vc);
                }
            }

            // S^T = K Q^T: D[key=quad*4+reg (+16nt)][query=r16]
            f32x4 accS[4];
            #pragma unroll
            for (int nt = 0; nt < 4; ++nt) accS[nt] = (f32x4)0.0f;
            #pragma unroll
            for (int nt = 0; nt < 4; ++nt)
                #pragma unroll
                for (int kk = 0; kk < 4; ++kk) {
                    bhalf8 kf = *(bhalf8*)&sK[nt * 16 + r16][kk * 32 + quad * 8];
                    accS[nt] = mfma16(kf, qf[kk], accS[nt]);
                }
            if (kt == qt) {   // causal: key > query masked
                #pragma unroll
                for (int nt = 0; nt < 4; ++nt)
                    #pragma unroll
                    for (int r = 0; r < 4; ++r)
                        if (nt * 16 + quad * 4 + r > wave * 16 + r16) accS[nt][r] = -1e30f;
            }

            // online softmax: all 16 values per lane share query r16
            float mx = -1e30f;
            #pragma unroll
            for (int nt = 0; nt < 4; ++nt)
                #pragma unroll
                for (int r = 0; r < 4; ++r) mx = fmaxf(mx, accS[nt][r]);
            mx = fmaxf(mx, __shfl_xor(mx, 16, 64));
            mx = fmaxf(mx, __shfl_xor(mx, 32, 64));
            const float mnew = fmaxf(m_i, mx);
            const float alpha = exp2f(m_i - mnew);
            m_i = mnew;

            float rs = 0.0f;
            #pragma unroll
            for (int nt = 0; nt < 4; ++nt) {
                bhalf4 pk;
                #pragma unroll
                for (int r = 0; r < 4; ++r) {
                    float p = exp2f(accS[nt][r] - mnew);
                    rs += p;
                    pk[r] = (bhalf)p;
                }
                *(bhalf4*)&sP[wave][r16][nt * 16 + quad * 4] = pk;
            }
            rs += __shfl_xor(rs, 16, 64);
            rs += __shfl_xor(rs, 32, 64);
            l_i = l_i * alpha + rs;

            // rescale O: alpha for row q=quad*4+r gathered from lane with r16==q
            float alphar[4];
            #pragma unroll
            for (int r = 0; r < 4; ++r) alphar[r] = __shfl(alpha, gat | (quad * 4 + r), 64);
            #pragma unroll
            for (int dt = 0; dt < 8; ++dt)
                #pragma unroll
                for (int r = 0; r < 4; ++r) accO[dt][r] *= alphar[r];

            // O += P V (P as A-operand from per-wave LDS buffer)
            #pragma unroll
            for (int kk2 = 0; kk2 < 2; ++kk2) {
                bhalf8 pf = *(bhalf8*)&sP[wave][r16][kk2 * 32 + quad * 8];
                #pragma unroll
                for (int dt = 0; dt < 8; ++dt) {
                    bhalf8 vf = *(bhalf8*)&sV[dt * 16 + r16][kk2 * 32 + quad * 8];
                    accO[dt] = mfma16(pf, vf, accO[dt]);
                }
            }
        }

        const float linv = 1.0f / l_i;
        float inv[4];
        #pragma unroll
        for (int r = 0; r < 4; ++r) inv[r] = __shfl(linv, gat | (quad * 4 + r), 64);
        const size_t obase = ((size_t)b * SEQ + qt * 64 + wave * 16) * (size_t)(N_HEADS * HD) + h * HD;
        #pragma unroll
        for (int dt = 0; dt < 8; ++dt)
            #pragma unroll
            for (int r = 0; r < 4; ++r)
                ob[obase + (size_t)(quad * 4 + r) * (N_HEADS * HD) + dt * 16 + r16] =
                    (bhalf)(accO[dt][r] * inv[r]);
    }
}

extern "C" void kernel_launch(void* const* d_in, const int* in_sizes, int n_in,
                              void* d_out, int out_size, void* d_ws, size_t ws_size,
                              hipStream_t stream) {
    const float* x      = (const float*)d_in[0];
    const float* freqs  = (const float*)d_in[1];
    const float* norm_w = (const float*)d_in[2];
    const float* wqkv   = (const float*)d_in[3];
    const float* wo     = (const float*)d_in[4];
    float* out = (float*)d_out;

    char* ws = (char*)d_ws;
    bhalf* wqkv_b = (bhalf*)(ws);                      // 12,582,912
    bhalf* wo_b   = (bhalf*)(ws + 12582912);           //  8,388,608
    bhalf* xn     = (bhalf*)(ws + 20971520);           // 16,777,216
    float* qkv    = (float*)(ws + 37748736);           // 50,331,648
    bhalf* qb     = (bhalf*)(ws + 88080384);           // 16,777,216
    bhalf* kb     = (bhalf*)(ws + 104857600);          //  4,194,304
    bhalf* vtb    = (bhalf*)(ws + 109051904);          //  4,194,304
    bhalf* attn   = (bhalf*)(ws + 113246208);          // 16,777,216

    cvt_w<<<10240, 256, 0, stream>>>(wqkv, wo, wqkv_b);
    rmsnorm_k<<<BATCH * SEQ, 256, 0, stream>>>(x, norm_w, xn);
    gemm_abt<<<dim3(24, 32), 256, 0, stream>>>(xn, wqkv_b, qkv, 3072, 2048);
    rope_k<<<BATCH * SEQ, 256, 0, stream>>>(qkv, freqs, qb, kb, vtb);
    attn_k<<<512, 256, 0, stream>>>(qb, kb, vtb, attn);
    gemm_abt<<<dim3(16, 32), 256, 0, stream>>>(attn, wo_b, out, 2048, 2048);
}

// Round 5
// 336.025 us; speedup vs baseline: 1.1299x; 1.0158x over previous
//
#include <hip/hip_runtime.h>
#include <cstdint>
#include <cstddef>

typedef __bf16 bhalf;
typedef __bf16 bhalf8 __attribute__((ext_vector_type(8)));
typedef __bf16 bhalf4 __attribute__((ext_vector_type(4)));
typedef float f32x4 __attribute__((ext_vector_type(4)));
typedef float f32x16 __attribute__((ext_vector_type(16)));

#define RMS_EPS 1e-6f
#define N_HEADS 16
#define N_KV 4
#define HD 128
#define DIM 2048
#define SEQ 2048
#define BATCH 2

static __device__ __forceinline__ f32x4 mfma16(bhalf8 a, bhalf8 b, f32x4 c) {
    return __builtin_amdgcn_mfma_f32_16x16x32_bf16(a, b, c, 0, 0, 0);
}
static __device__ __forceinline__ f32x16 mfma32(bhalf8 a, bhalf8 b, f32x16 c) {
    return __builtin_amdgcn_mfma_f32_32x32x16_bf16(a, b, c, 0, 0, 0);
}

// async global->LDS, 16B per lane; LDS base wave-uniform (HW adds lane*16)
static __device__ __forceinline__ void gload16(const bhalf* g, bhalf* l) {
    __builtin_amdgcn_global_load_lds((const __attribute__((address_space(1))) unsigned int*)g,
                                     (__attribute__((address_space(3))) unsigned int*)l,
                                     16, 0, 0);
}

// ---------------- weight convert f32 -> bf16 ----------------
__global__ __launch_bounds__(256) void cvt_w(const float* __restrict__ a,
                                             const float* __restrict__ b,
                                             bhalf* __restrict__ dst) {
    size_t i = ((size_t)blockIdx.x * 256 + threadIdx.x) * 4;
    const size_t NQ = (size_t)3072 * 2048;
    float4 v = (i < NQ) ? ((const float4*)a)[i >> 2] : ((const float4*)b)[(i - NQ) >> 2];
    bhalf4 o;
    o[0] = (bhalf)v.x; o[1] = (bhalf)v.y; o[2] = (bhalf)v.z; o[3] = (bhalf)v.w;
    *(bhalf4*)(dst + i) = o;
}

// ---------------- RMSNorm: one block per row ----------------
__global__ __launch_bounds__(256) void rmsnorm_k(const float* __restrict__ x,
                                                 const float* __restrict__ w,
                                                 bhalf* __restrict__ xn) {
    const int row = blockIdx.x;
    const int tid = threadIdx.x;
    const float4* xr = (const float4*)(x + (size_t)row * DIM);
    float4 v0 = xr[tid * 2], v1 = xr[tid * 2 + 1];
    float ss = v0.x * v0.x + v0.y * v0.y + v0.z * v0.z + v0.w * v0.w
             + v1.x * v1.x + v1.y * v1.y + v1.z * v1.z + v1.w * v1.w;
    #pragma unroll
    for (int off = 32; off; off >>= 1) ss += __shfl_xor(ss, off, 64);
    __shared__ float red[4];
    if ((tid & 63) == 0) red[tid >> 6] = ss;
    __syncthreads();
    float tot = red[0] + red[1] + red[2] + red[3];
    float scale = rsqrtf(tot * (1.0f / DIM) + RMS_EPS);
    const float4* wr = (const float4*)w;
    float4 w0 = wr[tid * 2], w1 = wr[tid * 2 + 1];
    bhalf8 o;
    o[0] = (bhalf)(v0.x * scale * w0.x); o[1] = (bhalf)(v0.y * scale * w0.y);
    o[2] = (bhalf)(v0.z * scale * w0.z); o[3] = (bhalf)(v0.w * scale * w0.w);
    o[4] = (bhalf)(v1.x * scale * w1.x); o[5] = (bhalf)(v1.y * scale * w1.y);
    o[6] = (bhalf)(v1.z * scale * w1.z); o[7] = (bhalf)(v1.w * scale * w1.w);
    *(bhalf8*)(xn + (size_t)row * DIM + tid * 8) = o;
}

// ---------------- GEMM C = A * B^T (m97 structure), templated epilogue -----
template <typename OutT>
__global__ __launch_bounds__(256) void gemm_abt(const bhalf* __restrict__ A,
                                                const bhalf* __restrict__ B,
                                                OutT* __restrict__ C,
                                                int N, int K) {
    const int tid = threadIdx.x;
    const int wave = tid >> 6, lane = tid & 63;
    const int quad = lane >> 4, r16 = lane & 15;
    const int m0 = blockIdx.y * 128, n0 = blockIdx.x * 128;
    const int wm = (wave >> 1) * 64, wn = (wave & 1) * 64;

    __shared__ __align__(16) bhalf sA[128][32];
    __shared__ __align__(16) bhalf sB[128][32];

    f32x4 acc[4][4];
    #pragma unroll
    for (int i = 0; i < 4; ++i)
        #pragma unroll
        for (int j = 0; j < 4; ++j) acc[i][j] = (f32x4)0.0f;

    const int lrow = lane >> 2;
    const int lcol = (lane & 3) * 8;
    const int arow = 32 * wave + lrow;
    const bhalf* Ap = A + (size_t)(m0 + arow) * K + lcol;
    const bhalf* Bp = B + (size_t)(n0 + arow) * K + lcol;
    const size_t rs16 = (size_t)16 * K;
    bhalf* sAp0 = &sA[32 * wave][0];
    bhalf* sAp1 = &sA[32 * wave + 16][0];
    bhalf* sBp0 = &sB[32 * wave][0];
    bhalf* sBp1 = &sB[32 * wave + 16][0];

    for (int k0 = 0; k0 < K; k0 += 32) {
        __syncthreads();
        gload16(Ap + k0, sAp0);
        gload16(Ap + k0 + rs16, sAp1);
        gload16(Bp + k0, sBp0);
        gload16(Bp + k0 + rs16, sBp1);
        __syncthreads();
        bhalf8 af[4], bfr[4];
        #pragma unroll
        for (int i = 0; i < 4; ++i) af[i]  = *(bhalf8*)&sA[wm + i * 16 + r16][quad * 8];
        #pragma unroll
        for (int j = 0; j < 4; ++j) bfr[j] = *(bhalf8*)&sB[wn + j * 16 + r16][quad * 8];
        #pragma unroll
        for (int i = 0; i < 4; ++i)
            #pragma unroll
            for (int j = 0; j < 4; ++j)
                acc[i][j] = mfma16(af[i], bfr[j], acc[i][j]);
    }

    #pragma unroll
    for (int i = 0; i < 4; ++i) {
        const int rbase = m0 + wm + i * 16 + quad * 4;
        #pragma unroll
        for (int rr = 0; rr < 4; ++rr) {
            OutT* crow = C + (size_t)(rbase + rr) * N + n0 + wn + r16;
            #pragma unroll
            for (int j = 0; j < 4; ++j) crow[j * 16] = (OutT)acc[i][j][rr];
        }
    }
}

// ---------------- RoPE + repack q/k (bf16 qkv in), transpose v -------------
__global__ __launch_bounds__(256) void rope_k(const bhalf* __restrict__ qkv,
                                              const float* __restrict__ freqs,
                                              bhalf* __restrict__ qb,
                                              bhalf* __restrict__ kb,
                                              bhalf* __restrict__ vt) {
    const int bs = blockIdx.x;
    const int b = bs >> 11, s = bs & 2047;
    const bhalf* row = qkv + (size_t)bs * 3072;
    const int tid = threadIdx.x;

    {
        const int h = tid >> 4, d20 = (tid & 15) * 4;
        bhalf8 e = *(const bhalf8*)(row + h * HD + d20 * 2);
        const float* fp = freqs + (size_t)s * 128 + d20 * 2;
        float4 f0 = *(const float4*)fp;
        float4 f1 = *(const float4*)(fp + 4);
        bhalf8 o;
        o[0] = (bhalf)((float)e[0] * f0.x - (float)e[1] * f0.y);
        o[1] = (bhalf)((float)e[0] * f0.y + (float)e[1] * f0.x);
        o[2] = (bhalf)((float)e[2] * f0.z - (float)e[3] * f0.w);
        o[3] = (bhalf)((float)e[2] * f0.w + (float)e[3] * f0.z);
        o[4] = (bhalf)((float)e[4] * f1.x - (float)e[5] * f1.y);
        o[5] = (bhalf)((float)e[4] * f1.y + (float)e[5] * f1.x);
        o[6] = (bhalf)((float)e[6] * f1.z - (float)e[7] * f1.w);
        o[7] = (bhalf)((float)e[6] * f1.w + (float)e[7] * f1.z);
        *(bhalf8*)(qb + ((size_t)(b * N_HEADS + h) * SEQ + s) * HD + d20 * 2) = o;
    }
    if (tid < 64) {
        const int kh = tid >> 4, d20 = (tid & 15) * 4;
        bhalf8 e = *(const bhalf8*)(row + 2048 + kh * HD + d20 * 2);
        const float* fp = freqs + (size_t)s * 128 + d20 * 2;
        float4 f0 = *(const float4*)fp;
        float4 f1 = *(const float4*)(fp + 4);
        bhalf8 o;
        o[0] = (bhalf)((float)e[0] * f0.x - (float)e[1] * f0.y);
        o[1] = (bhalf)((float)e[0] * f0.y + (float)e[1] * f0.x);
        o[2] = (bhalf)((float)e[2] * f0.z - (float)e[3] * f0.w);
        o[3] = (bhalf)((float)e[2] * f0.w + (float)e[3] * f0.z);
        o[4] = (bhalf)((float)e[4] * f1.x - (float)e[5] * f1.y);
        o[5] = (bhalf)((float)e[4] * f1.y + (float)e[5] * f1.x);
        o[6] = (bhalf)((float)e[6] * f1.z - (float)e[7] * f1.w);
        o[7] = (bhalf)((float)e[6] * f1.w + (float)e[7] * f1.z);
        *(bhalf8*)(kb + ((size_t)(b * N_KV + kh) * SEQ + s) * HD + d20 * 2) = o;
    }
    for (int e = tid; e < 512; e += 256) {
        const int kh = e >> 7, d = e & 127;
        vt[((size_t)(b * N_KV + kh) * HD + d) * SEQ + s] = row[2560 + e];
    }
}

// ---------------- Flash attention: 32x32 MFMA, S^T/O^T, query-on-lane ------
// grid 256 = pair(8) | h(16) | b(2); block handles 128-row q-tiles t and 15-t
// (exactly 34 k-iters each). 4 waves x 32 q-rows. Query lives on lane&31 for
// BOTH S^T (=K Q^T) and O^T (=V^T P^T): softmax needs 1 shuffle, no gathers.
__global__ __launch_bounds__(256, 1) void attn_k(const bhalf* __restrict__ qb,
                                                 const bhalf* __restrict__ kb,
                                                 const bhalf* __restrict__ vt,
                                                 bhalf* __restrict__ ob) {
    const int tid = threadIdx.x;
    const int wave = tid >> 6, lane = tid & 63;
    const int l31 = lane & 31, h2 = lane >> 5;
    const int pair = blockIdx.x & 7;
    const int hh = (blockIdx.x >> 3) & 15;
    const int b = blockIdx.x >> 7;
    const int kvh = hh >> 2;

    __shared__ __align__(16) bhalf sK[64][136];
    __shared__ __align__(16) bhalf sV[128][72];
    __shared__ __align__(16) bhalf sP[4][32][72];

    const bhalf* Kbase = kb + (size_t)(b * N_KV + kvh) * SEQ * HD;
    const bhalf* Vbase = vt + (size_t)(b * N_KV + kvh) * HD * SEQ;
    const float SCL2 = 0.08838834764831845f * 1.4426950408889634f;

    const int kr = tid >> 4, kc = (tid & 15) * 8;   // K rows kr+16i, col kc
    const int vr = tid >> 3, vc = (tid & 7) * 8;    // V^T rows vr+32i, col vc

    for (int phase = 0; phase < 2; ++phase) {
        const int qt = phase ? (15 - pair) : pair;
        const int ktmax = 2 * qt + 1;
        const int qrow = qt * 128 + wave * 32 + l31;

        // Q B-operand frags: B[k][n]: n=l31(query), k=h2*8+j within 16-chunk
        const bhalf* qbase = qb + (((size_t)(b * N_HEADS + hh) * SEQ) + qrow) * HD;
        bhalf8 qf[8];
        #pragma unroll
        for (int kk = 0; kk < 8; ++kk) {
            bhalf8 q0 = *(const bhalf8*)(qbase + kk * 16 + h2 * 8);
            #pragma unroll
            for (int e = 0; e < 8; ++e) q0[e] = (bhalf)((float)q0[e] * SCL2);
            qf[kk] = q0;
        }

        f32x16 accO[4];
        #pragma unroll
        for (int dt = 0; dt < 4; ++dt) accO[dt] = (f32x16)0.0f;
        float m_i = -1e30f, l_i = 0.0f;   // stats for query l31 (dup over h2)

        bhalf8 kreg[4], vreg[4];
        #pragma unroll
        for (int i = 0; i < 4; ++i) {
            kreg[i] = *(const bhalf8*)(Kbase + (size_t)(kr + 16 * i) * HD + kc);
            vreg[i] = *(const bhalf8*)(Vbase + (size_t)(vr + 32 * i) * SEQ + vc);
        }

        for (int kt = 0; kt <= ktmax; ++kt) {
            __syncthreads();
            #pragma unroll
            for (int i = 0; i < 4; ++i) {
                *(bhalf8*)&sK[kr + 16 * i][kc] = kreg[i];
                *(bhalf8*)&sV[vr + 32 * i][vc] = vreg[i];
            }
            __syncthreads();
            if (kt < ktmax) {
                const int kn = (kt + 1) * 64;
                #pragma unroll
                for (int i = 0; i < 4; ++i) {
                    kreg[i] = *(const bhalf8*)(Kbase + (size_t)(kn + kr + 16 * i) * HD + kc);
                    vreg[i] = *(const bhalf8*)(Vbase + (size_t)(vr + 32 * i) * SEQ + kn + vc);
                }
            }

            // wave fully above diagonal on this tile? (barriers already done)
            if (qt * 128 + wave * 32 + 31 < kt * 64) continue;

            // S^T = K Q^T: D[key = (r&3)+8*(r>>2)+4*h2 (+32nt)][query = l31]
            f32x16 accS[2];
            accS[0] = (f32x16)0.0f; accS[1] = (f32x16)0.0f;
            #pragma unroll
            for (int kk = 0; kk < 8; ++kk) {
                bhalf8 kf0 = *(bhalf8*)&sK[l31][kk * 16 + h2 * 8];
                bhalf8 kf1 = *(bhalf8*)&sK[32 + l31][kk * 16 + h2 * 8];
                accS[0] = mfma32(kf0, qf[kk], accS[0]);
                accS[1] = mfma32(kf1, qf[kk], accS[1]);
            }
            if (kt * 64 + 63 > qt * 128 + wave * 32) {   // diagonal-crossing
                #pragma unroll
                for (int nt = 0; nt < 2; ++nt)
                    #pragma unroll
                    for (int r = 0; r < 16; ++r) {
                        const int key = kt * 64 + nt * 32 + (r & 3) + 8 * (r >> 2) + 4 * h2;
                        if (key > qrow) accS[nt][r] = -1e30f;
                    }
            }

            // online softmax: all 32 scores per lane share query l31
            float mx = -1e30f;
            #pragma unroll
            for (int nt = 0; nt < 2; ++nt)
                #pragma unroll
                for (int r = 0; r < 16; ++r) mx = fmaxf(mx, accS[nt][r]);
            mx = fmaxf(mx, __shfl_xor(mx, 32, 64));
            const float mnew = fmaxf(m_i, mx);
            const float alpha = exp2f(m_i - mnew);
            m_i = mnew;

            float rs = 0.0f;
            #pragma unroll
            for (int nt = 0; nt < 2; ++nt)
                #pragma unroll
                for (int c = 0; c < 4; ++c) {
                    bhalf4 pk;
                    #pragma unroll
                    for (int r = 0; r < 4; ++r) {
                        float p = exp2f(accS[nt][c * 4 + r] - mnew);
                        rs += p;
                        pk[r] = (bhalf)p;
                    }
                    *(bhalf4*)&sP[wave][l31][nt * 32 + c * 8 + h2 * 4] = pk;
                }
            rs += __shfl_xor(rs, 32, 64);
            l_i = l_i * alpha + rs;

            #pragma unroll
            for (int dt = 0; dt < 4; ++dt)
                #pragma unroll
                for (int r = 0; r < 16; ++r) accO[dt][r] *= alpha;

            // O^T = V^T P^T: A = V^T[d][key], B = P^T[key][q]; sP per-wave
            #pragma unroll
            for (int kk2 = 0; kk2 < 4; ++kk2) {
                bhalf8 pf = *(bhalf8*)&sP[wave][l31][kk2 * 16 + h2 * 8];
                #pragma unroll
                for (int dt = 0; dt < 4; ++dt) {
                    bhalf8 vf = *(bhalf8*)&sV[dt * 32 + l31][kk2 * 16 + h2 * 8];
                    accO[dt] = mfma32(vf, pf, accO[dt]);
                }
            }
        }

        const float inv = 1.0f / l_i;
        bhalf* obase = ob + ((size_t)b * SEQ + qrow) * (size_t)(N_HEADS * HD) + hh * HD;
        #pragma unroll
        for (int dt = 0; dt < 4; ++dt)
            #pragma unroll
            for (int c = 0; c < 4; ++c) {
                bhalf4 o4;
                #pragma unroll
                for (int r = 0; r < 4; ++r) o4[r] = (bhalf)(accO[dt][c * 4 + r] * inv);
                *(bhalf4*)(obase + dt * 32 + c * 8 + h2 * 4) = o4;
            }
    }
}

extern "C" void kernel_launch(void* const* d_in, const int* in_sizes, int n_in,
                              void* d_out, int out_size, void* d_ws, size_t ws_size,
                              hipStream_t stream) {
    const float* x      = (const float*)d_in[0];
    const float* freqs  = (const float*)d_in[1];
    const float* norm_w = (const float*)d_in[2];
    const float* wqkv   = (const float*)d_in[3];
    const float* wo     = (const float*)d_in[4];
    float* out = (float*)d_out;

    char* ws = (char*)d_ws;
    bhalf* wqkv_b = (bhalf*)(ws);                      // 12,582,912
    bhalf* wo_b   = (bhalf*)(ws + 12582912);           //  8,388,608
    bhalf* xn     = (bhalf*)(ws + 20971520);           // 16,777,216
    bhalf* qkv    = (bhalf*)(ws + 37748736);           // 25,165,824 (bf16 now)
    bhalf* qb     = (bhalf*)(ws + 88080384);           // 16,777,216
    bhalf* kb     = (bhalf*)(ws + 104857600);          //  4,194,304
    bhalf* vtb    = (bhalf*)(ws + 109051904);          //  4,194,304
    bhalf* attn   = (bhalf*)(ws + 113246208);          // 16,777,216

    cvt_w<<<10240, 256, 0, stream>>>(wqkv, wo, wqkv_b);
    rmsnorm_k<<<BATCH * SEQ, 256, 0, stream>>>(x, norm_w, xn);
    gemm_abt<bhalf><<<dim3(24, 32), 256, 0, stream>>>(xn, wqkv_b, qkv, 3072, 2048);
    rope_k<<<BATCH * SEQ, 256, 0, stream>>>(qkv, freqs, qb, kb, vtb);
    attn_k<<<256, 256, 0, stream>>>(qb, kb, vtb, attn);
    gemm_abt<float><<<dim3(16, 32), 256, 0, stream>>>(attn, wo_b, out, 2048, 2048);
}

// Round 6
// 319.397 us; speedup vs baseline: 1.1888x; 1.0521x over previous
//
#include <hip/hip_runtime.h>
#include <cstdint>
#include <cstddef>

typedef __bf16 bhalf;
typedef __bf16 bhalf8 __attribute__((ext_vector_type(8)));
typedef __bf16 bhalf4 __attribute__((ext_vector_type(4)));
typedef float f32x4 __attribute__((ext_vector_type(4)));
typedef float f32x16 __attribute__((ext_vector_type(16)));

#define RMS_EPS 1e-6f
#define N_HEADS 16
#define N_KV 4
#define HD 128
#define DIM 2048
#define SEQ 2048
#define BATCH 2

static __device__ __forceinline__ f32x4 mfma16(bhalf8 a, bhalf8 b, f32x4 c) {
    return __builtin_amdgcn_mfma_f32_16x16x32_bf16(a, b, c, 0, 0, 0);
}
static __device__ __forceinline__ f32x16 mfma32(bhalf8 a, bhalf8 b, f32x16 c) {
    return __builtin_amdgcn_mfma_f32_32x32x16_bf16(a, b, c, 0, 0, 0);
}

// async global->LDS, 16B per lane; LDS base wave-uniform (HW adds lane*16)
static __device__ __forceinline__ void gload16(const bhalf* g, bhalf* l) {
    __builtin_amdgcn_global_load_lds((const __attribute__((address_space(1))) unsigned int*)g,
                                     (__attribute__((address_space(3))) unsigned int*)l,
                                     16, 0, 0);
}

// ---------------- weight convert f32 -> bf16 ----------------
__global__ __launch_bounds__(256) void cvt_w(const float* __restrict__ a,
                                             const float* __restrict__ b,
                                             bhalf* __restrict__ dst) {
    size_t i = ((size_t)blockIdx.x * 256 + threadIdx.x) * 4;
    const size_t NQ = (size_t)3072 * 2048;
    float4 v = (i < NQ) ? ((const float4*)a)[i >> 2] : ((const float4*)b)[(i - NQ) >> 2];
    bhalf4 o;
    o[0] = (bhalf)v.x; o[1] = (bhalf)v.y; o[2] = (bhalf)v.z; o[3] = (bhalf)v.w;
    *(bhalf4*)(dst + i) = o;
}

// ---------------- RMSNorm: one block per row ----------------
__global__ __launch_bounds__(256) void rmsnorm_k(const float* __restrict__ x,
                                                 const float* __restrict__ w,
                                                 bhalf* __restrict__ xn) {
    const int row = blockIdx.x;
    const int tid = threadIdx.x;
    const float4* xr = (const float4*)(x + (size_t)row * DIM);
    float4 v0 = xr[tid * 2], v1 = xr[tid * 2 + 1];
    float ss = v0.x * v0.x + v0.y * v0.y + v0.z * v0.z + v0.w * v0.w
             + v1.x * v1.x + v1.y * v1.y + v1.z * v1.z + v1.w * v1.w;
    #pragma unroll
    for (int off = 32; off; off >>= 1) ss += __shfl_xor(ss, off, 64);
    __shared__ float red[4];
    if ((tid & 63) == 0) red[tid >> 6] = ss;
    __syncthreads();
    float tot = red[0] + red[1] + red[2] + red[3];
    float scale = rsqrtf(tot * (1.0f / DIM) + RMS_EPS);
    const float4* wr = (const float4*)w;
    float4 w0 = wr[tid * 2], w1 = wr[tid * 2 + 1];
    bhalf8 o;
    o[0] = (bhalf)(v0.x * scale * w0.x); o[1] = (bhalf)(v0.y * scale * w0.y);
    o[2] = (bhalf)(v0.z * scale * w0.z); o[3] = (bhalf)(v0.w * scale * w0.w);
    o[4] = (bhalf)(v1.x * scale * w1.x); o[5] = (bhalf)(v1.y * scale * w1.y);
    o[6] = (bhalf)(v1.z * scale * w1.z); o[7] = (bhalf)(v1.w * scale * w1.w);
    *(bhalf8*)(xn + (size_t)row * DIM + tid * 8) = o;
}

// ---------------- GEMM C = A * B^T (m97 structure), templated epilogue -----
template <typename OutT>
__global__ __launch_bounds__(256) void gemm_abt(const bhalf* __restrict__ A,
                                                const bhalf* __restrict__ B,
                                                OutT* __restrict__ C,
                                                int N, int K) {
    const int tid = threadIdx.x;
    const int wave = tid >> 6, lane = tid & 63;
    const int quad = lane >> 4, r16 = lane & 15;
    const int m0 = blockIdx.y * 128, n0 = blockIdx.x * 128;
    const int wm = (wave >> 1) * 64, wn = (wave & 1) * 64;

    __shared__ __align__(16) bhalf sA[128][32];
    __shared__ __align__(16) bhalf sB[128][32];

    f32x4 acc[4][4];
    #pragma unroll
    for (int i = 0; i < 4; ++i)
        #pragma unroll
        for (int j = 0; j < 4; ++j) acc[i][j] = (f32x4)0.0f;

    const int lrow = lane >> 2;
    const int lcol = (lane & 3) * 8;
    const int arow = 32 * wave + lrow;
    const bhalf* Ap = A + (size_t)(m0 + arow) * K + lcol;
    const bhalf* Bp = B + (size_t)(n0 + arow) * K + lcol;
    const size_t rs16 = (size_t)16 * K;
    bhalf* sAp0 = &sA[32 * wave][0];
    bhalf* sAp1 = &sA[32 * wave + 16][0];
    bhalf* sBp0 = &sB[32 * wave][0];
    bhalf* sBp1 = &sB[32 * wave + 16][0];

    for (int k0 = 0; k0 < K; k0 += 32) {
        __syncthreads();
        gload16(Ap + k0, sAp0);
        gload16(Ap + k0 + rs16, sAp1);
        gload16(Bp + k0, sBp0);
        gload16(Bp + k0 + rs16, sBp1);
        __syncthreads();
        bhalf8 af[4], bfr[4];
        #pragma unroll
        for (int i = 0; i < 4; ++i) af[i]  = *(bhalf8*)&sA[wm + i * 16 + r16][quad * 8];
        #pragma unroll
        for (int j = 0; j < 4; ++j) bfr[j] = *(bhalf8*)&sB[wn + j * 16 + r16][quad * 8];
        #pragma unroll
        for (int i = 0; i < 4; ++i)
            #pragma unroll
            for (int j = 0; j < 4; ++j)
                acc[i][j] = mfma16(af[i], bfr[j], acc[i][j]);
    }

    #pragma unroll
    for (int i = 0; i < 4; ++i) {
        const int rbase = m0 + wm + i * 16 + quad * 4;
        #pragma unroll
        for (int rr = 0; rr < 4; ++rr) {
            OutT* crow = C + (size_t)(rbase + rr) * N + n0 + wn + r16;
            #pragma unroll
            for (int j = 0; j < 4; ++j) crow[j * 16] = (OutT)acc[i][j][rr];
        }
    }
}

// ---------------- RoPE + repack q/k (bf16 qkv in), transpose v -------------
__global__ __launch_bounds__(256) void rope_k(const bhalf* __restrict__ qkv,
                                              const float* __restrict__ freqs,
                                              bhalf* __restrict__ qb,
                                              bhalf* __restrict__ kb,
                                              bhalf* __restrict__ vt) {
    const int bs = blockIdx.x;
    const int b = bs >> 11, s = bs & 2047;
    const bhalf* row = qkv + (size_t)bs * 3072;
    const int tid = threadIdx.x;

    {
        const int h = tid >> 4, d20 = (tid & 15) * 4;
        bhalf8 e = *(const bhalf8*)(row + h * HD + d20 * 2);
        const float* fp = freqs + (size_t)s * 128 + d20 * 2;
        float4 f0 = *(const float4*)fp;
        float4 f1 = *(const float4*)(fp + 4);
        bhalf8 o;
        o[0] = (bhalf)((float)e[0] * f0.x - (float)e[1] * f0.y);
        o[1] = (bhalf)((float)e[0] * f0.y + (float)e[1] * f0.x);
        o[2] = (bhalf)((float)e[2] * f0.z - (float)e[3] * f0.w);
        o[3] = (bhalf)((float)e[2] * f0.w + (float)e[3] * f0.z);
        o[4] = (bhalf)((float)e[4] * f1.x - (float)e[5] * f1.y);
        o[5] = (bhalf)((float)e[4] * f1.y + (float)e[5] * f1.x);
        o[6] = (bhalf)((float)e[6] * f1.z - (float)e[7] * f1.w);
        o[7] = (bhalf)((float)e[6] * f1.w + (float)e[7] * f1.z);
        *(bhalf8*)(qb + ((size_t)(b * N_HEADS + h) * SEQ + s) * HD + d20 * 2) = o;
    }
    if (tid < 64) {
        const int kh = tid >> 4, d20 = (tid & 15) * 4;
        bhalf8 e = *(const bhalf8*)(row + 2048 + kh * HD + d20 * 2);
        const float* fp = freqs + (size_t)s * 128 + d20 * 2;
        float4 f0 = *(const float4*)fp;
        float4 f1 = *(const float4*)(fp + 4);
        bhalf8 o;
        o[0] = (bhalf)((float)e[0] * f0.x - (float)e[1] * f0.y);
        o[1] = (bhalf)((float)e[0] * f0.y + (float)e[1] * f0.x);
        o[2] = (bhalf)((float)e[2] * f0.z - (float)e[3] * f0.w);
        o[3] = (bhalf)((float)e[2] * f0.w + (float)e[3] * f0.z);
        o[4] = (bhalf)((float)e[4] * f1.x - (float)e[5] * f1.y);
        o[5] = (bhalf)((float)e[4] * f1.y + (float)e[5] * f1.x);
        o[6] = (bhalf)((float)e[6] * f1.z - (float)e[7] * f1.w);
        o[7] = (bhalf)((float)e[6] * f1.w + (float)e[7] * f1.z);
        *(bhalf8*)(kb + ((size_t)(b * N_KV + kh) * SEQ + s) * HD + d20 * 2) = o;
    }
    for (int e = tid; e < 512; e += 256) {
        const int kh = e >> 7, d = e & 127;
        vt[((size_t)(b * N_KV + kh) * HD + d) * SEQ + s] = row[2560 + e];
    }
}

// ---------------- Flash attention: 32x32 S^T/O^T + in-block key split ------
// grid 512 = pair(16) | h(16) | b(2) -> 2 blocks/CU, 2 waves/SIMD.
// Block: 64 q-rows (tiles t and 31-t; exactly 33 k-iters). 4 waves =
// qw(2: 32 q-rows each) x kw(2: 32-key strip of each 64-key tile).
// Each wave keeps private online-softmax (m,l,accO) over its key strip;
// one LDS merge per phase (flash-decoding within the block).
__global__ __launch_bounds__(256, 2) void attn_k(const bhalf* __restrict__ qb,
                                                 const bhalf* __restrict__ kb,
                                                 const bhalf* __restrict__ vt,
                                                 bhalf* __restrict__ ob) {
    const int tid = threadIdx.x;
    const int wave = tid >> 6, lane = tid & 63;
    const int l31 = lane & 31, h2 = lane >> 5;
    const int qw = wave & 1, kw = wave >> 1;
    const int pair = blockIdx.x & 15;
    const int hh = (blockIdx.x >> 4) & 15;
    const int b = blockIdx.x >> 8;
    const int kvh = hh >> 2;

    // sK 64x136 (8704) | sV 128x72 (9216) | sP 4x32x40 (5120) = 23040 elems
    __shared__ __align__(16) bhalf smem[23040];
    bhalf (*sK)[136] = (bhalf(*)[136])smem;
    bhalf (*sV)[72]  = (bhalf(*)[72])(smem + 8704);
    bhalf* sProw = smem + 17920 + (wave * 32 + l31) * 40;
    float* mrg = (float*)smem;   // phase-end merge buffer (aliases sK/sV)

    const bhalf* Kbase = kb + (size_t)(b * N_KV + kvh) * SEQ * HD;
    const bhalf* Vbase = vt + (size_t)(b * N_KV + kvh) * HD * SEQ;
    const float SCL2 = 0.08838834764831845f * 1.4426950408889634f;

    const int kr = tid >> 4, kc = (tid & 15) * 8;   // K rows kr+16i, col kc
    const int vr = tid >> 3, vc = (tid & 7) * 8;    // V^T rows vr+32i, col vc
    const int mbase = (qw * 64 + lane) * 66;         // merge slot

    for (int phase = 0; phase < 2; ++phase) {
        const int qt = phase ? (31 - pair) : pair;   // 64-row q-tile index
        const int qrow = qt * 64 + qw * 32 + l31;
        const int qhi = qt * 64 + qw * 32 + 31;

        // Q B-operand frags (n=l31 query, k=h2*8+j per 16-chunk), scale folded
        const bhalf* qbase = qb + (((size_t)(b * N_HEADS + hh) * SEQ) + qrow) * HD;
        bhalf8 qf[8];
        #pragma unroll
        for (int kk = 0; kk < 8; ++kk) {
            bhalf8 q0 = *(const bhalf8*)(qbase + kk * 16 + h2 * 8);
            #pragma unroll
            for (int e = 0; e < 8; ++e) q0[e] = (bhalf)((float)q0[e] * SCL2);
            qf[kk] = q0;
        }

        f32x16 accO[4];
        #pragma unroll
        for (int dt = 0; dt < 4; ++dt) accO[dt] = (f32x16)0.0f;
        float m_i = -1e30f, l_i = 0.0f;

        bhalf8 kreg[4], vreg[4];
        #pragma unroll
        for (int i = 0; i < 4; ++i) {
            kreg[i] = *(const bhalf8*)(Kbase + (size_t)(kr + 16 * i) * HD + kc);
            vreg[i] = *(const bhalf8*)(Vbase + (size_t)(vr + 32 * i) * SEQ + vc);
        }

        for (int kt = 0; kt <= qt; ++kt) {
            __syncthreads();
            #pragma unroll
            for (int i = 0; i < 4; ++i) {
                *(bhalf8*)&sK[kr + 16 * i][kc] = kreg[i];
                *(bhalf8*)&sV[vr + 32 * i][vc] = vreg[i];
            }
            __syncthreads();
            if (kt < qt) {
                const int kn = (kt + 1) * 64;
                #pragma unroll
                for (int i = 0; i < 4; ++i) {
                    kreg[i] = *(const bhalf8*)(Kbase + (size_t)(kn + kr + 16 * i) * HD + kc);
                    vreg[i] = *(const bhalf8*)(Vbase + (size_t)(vr + 32 * i) * SEQ + kn + vc);
                }
            }
            // strip entirely above the diagonal? (barriers already done)
            if (qhi < kt * 64 + kw * 32) continue;

            // S^T = K Q^T for this wave's 32-key strip
            f32x16 accS = (f32x16)0.0f;
            const bhalf* kRow = &sK[kw * 32 + l31][0];
            #pragma unroll
            for (int kk = 0; kk < 8; ++kk)
                accS = mfma32(*(bhalf8*)(kRow + kk * 16 + h2 * 8), qf[kk], accS);

            if (kt == qt) {   // diagonal tile: mask key > query
                #pragma unroll
                for (int r = 0; r < 16; ++r) {
                    const int key = kt * 64 + kw * 32 + (r & 3) + 8 * (r >> 2) + 4 * h2;
                    if (key > qrow) accS[r] = -1e30f;
                }
            }

            // online softmax (query = l31, dup over h2: 1 shuffle)
            float mx = -1e30f;
            #pragma unroll
            for (int r = 0; r < 16; ++r) mx = fmaxf(mx, accS[r]);
            mx = fmaxf(mx, __shfl_xor(mx, 32, 64));
            const float mnew = fmaxf(m_i, mx);
            const float alpha = __builtin_amdgcn_exp2f(m_i - mnew);
            m_i = mnew;

            float rs = 0.0f;
            #pragma unroll
            for (int c = 0; c < 4; ++c) {
                bhalf4 pk;
                #pragma unroll
                for (int rr = 0; rr < 4; ++rr) {
                    float p = __builtin_amdgcn_exp2f(accS[c * 4 + rr] - mnew);
                    rs += p;
                    pk[rr] = (bhalf)p;
                }
                *(bhalf4*)(sProw + c * 8 + h2 * 4) = pk;   // key_local = 8c+4h2+rr
            }
            rs += __shfl_xor(rs, 32, 64);
            l_i = l_i * alpha + rs;

            #pragma unroll
            for (int dt = 0; dt < 4; ++dt)
                #pragma unroll
                for (int r = 0; r < 16; ++r) accO[dt][r] *= alpha;

            // O^T += V^T(strip) P^T  (sP is per-wave: no barrier needed)
            #pragma unroll
            for (int kk2 = 0; kk2 < 2; ++kk2) {
                bhalf8 pf = *(bhalf8*)(sProw + kk2 * 16 + h2 * 8);
                #pragma unroll
                for (int dt = 0; dt < 4; ++dt) {
                    bhalf8 vf = *(bhalf8*)&sV[dt * 32 + l31][kw * 32 + kk2 * 16 + h2 * 8];
                    accO[dt] = mfma32(vf, pf, accO[dt]);
                }
            }
        }

        // ---- merge the two key-split halves (kw=1 -> kw=0) via LDS ----
        __syncthreads();
        if (kw == 1) {
            #pragma unroll
            for (int dt = 0; dt < 4; ++dt)
                #pragma unroll
                for (int r = 0; r < 16; ++r) mrg[mbase + dt * 16 + r] = accO[dt][r];
            mrg[mbase + 64] = m_i;
            mrg[mbase + 65] = l_i;
        }
        __syncthreads();
        if (kw == 0) {
            const float m1 = mrg[mbase + 64];
            const float l1 = mrg[mbase + 65];
            const float m = fmaxf(m_i, m1);
            const float b0 = __builtin_amdgcn_exp2f(m_i - m);
            const float b1 = __builtin_amdgcn_exp2f(m1 - m);
            const float inv = 1.0f / (l_i * b0 + l1 * b1);
            bhalf* obase = ob + ((size_t)b * SEQ + qrow) * (size_t)(N_HEADS * HD) + hh * HD;
            #pragma unroll
            for (int dt = 0; dt < 4; ++dt)
                #pragma unroll
                for (int c = 0; c < 4; ++c) {
                    bhalf4 o4;
                    #pragma unroll
                    for (int rr = 0; rr < 4; ++rr) {
                        const float v = accO[dt][c * 4 + rr] * b0 +
                                        mrg[mbase + dt * 16 + c * 4 + rr] * b1;
                        o4[rr] = (bhalf)(v * inv);
                    }
                    *(bhalf4*)(obase + dt * 32 + c * 8 + h2 * 4) = o4;
                }
        }
    }
}

extern "C" void kernel_launch(void* const* d_in, const int* in_sizes, int n_in,
                              void* d_out, int out_size, void* d_ws, size_t ws_size,
                              hipStream_t stream) {
    const float* x      = (const float*)d_in[0];
    const float* freqs  = (const float*)d_in[1];
    const float* norm_w = (const float*)d_in[2];
    const float* wqkv   = (const float*)d_in[3];
    const float* wo     = (const float*)d_in[4];
    float* out = (float*)d_out;

    char* ws = (char*)d_ws;
    bhalf* wqkv_b = (bhalf*)(ws);                      // 12,582,912
    bhalf* wo_b   = (bhalf*)(ws + 12582912);           //  8,388,608
    bhalf* xn     = (bhalf*)(ws + 20971520);           // 16,777,216
    bhalf* qkv    = (bhalf*)(ws + 37748736);           // 25,165,824 (bf16)
    bhalf* qb     = (bhalf*)(ws + 88080384);           // 16,777,216
    bhalf* kb     = (bhalf*)(ws + 104857600);          //  4,194,304
    bhalf* vtb    = (bhalf*)(ws + 109051904);          //  4,194,304
    bhalf* attn   = (bhalf*)(ws + 113246208);          // 16,777,216

    cvt_w<<<10240, 256, 0, stream>>>(wqkv, wo, wqkv_b);
    rmsnorm_k<<<BATCH * SEQ, 256, 0, stream>>>(x, norm_w, xn);
    gemm_abt<bhalf><<<dim3(24, 32), 256, 0, stream>>>(xn, wqkv_b, qkv, 3072, 2048);
    rope_k<<<BATCH * SEQ, 256, 0, stream>>>(qkv, freqs, qb, kb, vtb);
    attn_k<<<512, 256, 0, stream>>>(qb, kb, vtb, attn);
    gemm_abt<float><<<dim3(16, 32), 256, 0, stream>>>(attn, wo_b, out, 2048, 2048);
}